// Round 21
// baseline (159.130 us; speedup 1.0000x reference)
//
#include <hip/hip_runtime.h>
#include <hip/hip_bf16.h>
#include <math.h>

#define FDIM 128

typedef __attribute__((ext_vector_type(8))) short short8v;
typedef __attribute__((ext_vector_type(4))) float f32x4;
typedef __attribute__((ext_vector_type(2))) float f32x2;

__device__ inline unsigned short f2b(float f) {
    union { float f; unsigned u; } c{f};
    unsigned r = c.u + 0x7fff + ((c.u >> 16) & 1);  // RNE
    return (unsigned short)(r >> 16);
}
__device__ inline float b2f(unsigned short b) {
    return __uint_as_float(((unsigned)b) << 16);
}
__device__ inline float elu_fast(float x) {
    return x > 0.f ? x : __expf(x) - 1.f;
}

__device__ inline void async_copy16(const void* gsrc, void* lds) {
    __builtin_amdgcn_global_load_lds(
        (const __attribute__((address_space(1))) unsigned int*)gsrc,
        (__attribute__((address_space(3))) unsigned int*)lds,
        16, 0, 0);
}

// ---------- zero scratch ----------
__global__ __launch_bounds__(256) void k_zero(int* __restrict__ p, int n) {
    int i = blockIdx.x * 256 + threadIdx.x;
    if (i < n) p[i] = 0;
}

// ---------- CSR build: histogram + per-edge slot capture ----------
__global__ __launch_bounds__(256) void k_deg(const int* __restrict__ dst,
                                             int* __restrict__ deg,
                                             unsigned short* __restrict__ slot, int E) {
    int e = blockIdx.x * 256 + threadIdx.x;
    if (e >= E) return;
    slot[e] = (unsigned short)atomicAdd(&deg[dst[e]], 1);
}

__global__ __launch_bounds__(256) void k_scan1(const int* __restrict__ deg,
                                               int* __restrict__ bsum, int V) {
    int i = blockIdx.x * 256 + threadIdx.x;
    int x = (i < V) ? deg[i] : 0;
#pragma unroll
    for (int o = 32; o; o >>= 1) x += __shfl_xor(x, o, 64);
    __shared__ int sh[4];
    int w = threadIdx.x >> 6, lane = threadIdx.x & 63;
    if (lane == 0) sh[w] = x;
    __syncthreads();
    if (threadIdx.x == 0) bsum[blockIdx.x] = sh[0] + sh[1] + sh[2] + sh[3];
}

__global__ __launch_bounds__(256) void k_scan2(int* __restrict__ bsum, int nb,
                                               int* __restrict__ row_start, int V) {
    __shared__ int sh[256];
    int t = threadIdx.x;
    int x = (t < nb) ? bsum[t] : 0;
    sh[t] = x;
    __syncthreads();
    int val = x;
    for (int o = 1; o < 256; o <<= 1) {
        int y = (t >= o) ? sh[t - o] : 0;
        __syncthreads();
        val += y;
        sh[t] = val;
        __syncthreads();
    }
    if (t < nb) bsum[t] = val - x;
    if (t == 255) row_start[V] = val;
}

__global__ __launch_bounds__(256) void k_scan3(const int* __restrict__ deg,
                                               const int* __restrict__ bsum,
                                               int* __restrict__ row_start, int V) {
    __shared__ int wsum[4];
    const int t = threadIdx.x;
    const int w = t >> 6, lane = t & 63;
    const int i = blockIdx.x * 256 + t;
    int x = (i < V) ? deg[i] : 0;
    int val = x;
#pragma unroll
    for (int o = 1; o < 64; o <<= 1) {
        int y = __shfl_up(val, o, 64);
        if (lane >= o) val += y;
    }
    if (lane == 63) wsum[w] = val;
    __syncthreads();
    int base = 0;
#pragma unroll
    for (int ww = 0; ww < 3; ww++)
        if (ww < w) base += wsum[ww];
    if (i < V) row_start[i] = bsum[blockIdx.x] + base + val - x;
}

// ---------- scatter pass A (atomic-free) ----------
__global__ __launch_bounds__(512) void k_scat1(const int* __restrict__ dst,
                                               const int* __restrict__ src,
                                               const float* __restrict__ logits,
                                               const int* __restrict__ row_start,
                                               const unsigned short* __restrict__ slot,
                                               int* __restrict__ bfill,
                                               uint2* __restrict__ staging, int E) {
    __shared__ int lhist[512];
    __shared__ int lscan[512];
    __shared__ int lgbase[512];
    __shared__ int wsum[8];
    __shared__ uint2 lrec[4096];
    __shared__ unsigned short lbkt[4096];
    const int t = threadIdx.x;
    const int wv = t >> 6, lane = t & 63;
    const int base = blockIdx.x * 4096;
    const int tot = min(4096, E - base);

    lhist[t] = 0;
    __syncthreads();

    uint2 rec[8];
    int bi[8], ri[8];
#pragma unroll
    for (int i = 0; i < 8; i++) {
        int e = base + i * 512 + t;
        if (e - base < tot) {
            int d = dst[e];
            int o = row_start[d] + (int)slot[e];
            rec[i].x = __float_as_uint(__expf(logits[e]));
            rec[i].y = ((unsigned)src[e] & 0xffffu) | ((unsigned)(o & 2047) << 16);
            bi[i] = o >> 11;
            ri[i] = atomicAdd(&lhist[bi[i]], 1);
        } else {
            bi[i] = -1;
        }
    }
    __syncthreads();

    int hv = lhist[t];
    int val = hv;
#pragma unroll
    for (int o = 1; o < 64; o <<= 1) {
        int y = __shfl_up(val, o, 64);
        if (lane >= o) val += y;
    }
    if (lane == 63) wsum[wv] = val;
    __syncthreads();
    int wbase = 0;
#pragma unroll
    for (int ww = 0; ww < 7; ww++)
        if (ww < wv) wbase += wsum[ww];
    int excl = wbase + val - hv;
    if (hv > 0) lgbase[t] = atomicAdd(&bfill[t], hv);
    lscan[t] = excl;
    __syncthreads();

#pragma unroll
    for (int i = 0; i < 8; i++) {
        if (bi[i] >= 0) {
            int pos = lscan[bi[i]] + ri[i];
            lrec[pos] = rec[i];
            lbkt[pos] = (unsigned short)bi[i];
        }
    }
    __syncthreads();

    for (int idx = t; idx < tot; idx += 512) {
        int b = lbkt[idx];
        int gp = (b << 11) + lgbase[b] + (idx - lscan[b]);
        staging[gp] = lrec[idx];
    }
}

// ---------- scatter pass B ----------
__global__ __launch_bounds__(256) void k_scat2(const uint2* __restrict__ staging,
                                               uint2* __restrict__ esort, int E) {
    __shared__ uint2 perm[2048];
    const int t = threadIdx.x;
    const int base = blockIdx.x << 11;
    const int n = min(2048, E - base);
    for (int i = t; i < n; i += 256) {
        uint2 r = staging[base + i];
        perm[r.y >> 16] = make_uint2(r.x, r.y & 0xffffu);
    }
    __syncthreads();
    for (int i = t; i < n; i += 256)
        esort[base + i] = perm[i];
}

__global__ __launch_bounds__(256) void k_prep_W(const float* __restrict__ W,
                                                unsigned short* __restrict__ Wb) {
    int i = blockIdx.x * 256 + threadIdx.x;  // 16384
    Wb[i] = f2b(W[i]);
}

// Bt layout: bucket (cgrp, ct, kc) of 512 shorts; within = q4*128 + l15*8 + j.
__global__ __launch_bounds__(256) void k_prep_B(const float* __restrict__ w_ih,
                                                const float* __restrict__ w_hh,
                                                unsigned short* __restrict__ Bt) {
    int i = blockIdx.x * 256 + threadIdx.x;  // 98304 shorts total
    if (i >= 98304) return;
    int bucket = i >> 9;
    int within = i & 511;
    int kc = bucket & 7;
    int ct = (bucket >> 3) % 3;
    int cgrp = bucket / 24;
    int q4 = within >> 7;
    int l15 = (within >> 3) & 15;
    int j = within & 7;
    int k = kc * 32 + q4 * 8 + j;
    int h = cgrp * 16 + l15;
    float v;
    if (ct < 2) {
        int jrow = ct * 128 + h;
        v = (k < 128) ? w_ih[(size_t)jrow * 128 + k]
                      : w_hh[(size_t)jrow * 128 + (k - 128)];
    } else {
        v = (kc < 4) ? w_ih[(size_t)(256 + h) * 128 + k]
                     : w_hh[(size_t)(256 + h) * 128 + (k - 128)];
    }
    Bt[i] = f2b(v);
}

// ---------- fused: nf(fp32) -> Xbf(bf16 right half) + hv(fp8) = fp8(nf @ W^T + b) ----------
__global__ __launch_bounds__(256) void k_hv(const float* __restrict__ nf,
                                            const unsigned short* __restrict__ Wb,
                                            const float* __restrict__ bias,
                                            unsigned short* __restrict__ Xbf,
                                            unsigned char* __restrict__ hvb, int V) {
    __shared__ unsigned short Wl[128][136];
    const int t = threadIdx.x;
    {
        int row = t >> 1, half = (t & 1) * 64;
        const float4* s = (const float4*)&Wb[row * 128 + half];
#pragma unroll
        for (int q = 0; q < 8; q++) {
            float4 v = s[q];
            *(float4*)&Wl[row][half + q * 8] = v;
        }
    }
    __syncthreads();
    const int w = t >> 6, lane = t & 63;
    const int row0 = blockIdx.x * 64 + w * 16;
    const int l15 = lane & 15, q4 = lane >> 4;
    int arow = row0 + l15;
    bool valid = arow < V;
    if (!valid) arow = V - 1;
    const int kl = q4 * 8;
    f32x4 acc[8];
#pragma unroll
    for (int i = 0; i < 8; i++) acc[i] = (f32x4)(0.f);

    for (int kc = 0; kc < 4; kc++) {
        // load fp32 nf, convert to bf16 in-register
        float4 v0 = *(const float4*)&nf[(size_t)arow * 128 + kc * 32 + kl];
        float4 v1 = *(const float4*)&nf[(size_t)arow * 128 + kc * 32 + kl + 4];
        short8v a;
        a[0] = (short)f2b(v0.x); a[1] = (short)f2b(v0.y);
        a[2] = (short)f2b(v0.z); a[3] = (short)f2b(v0.w);
        a[4] = (short)f2b(v1.x); a[5] = (short)f2b(v1.y);
        a[6] = (short)f2b(v1.z); a[7] = (short)f2b(v1.w);
        if (valid)
            *(short8v*)&Xbf[(size_t)arow * 256 + 128 + kc * 32 + kl] = a;
#pragma unroll
        for (int tile = 0; tile < 8; tile++) {
            short8v b = *(const short8v*)&Wl[tile * 16 + l15][kc * 32 + kl];
            acc[tile] = __builtin_amdgcn_mfma_f32_16x16x32_bf16(a, b, acc[tile], 0, 0, 0);
        }
    }
#pragma unroll
    for (int tile = 0; tile < 8; tile++) {
#pragma unroll
        for (int r = 0; r < 4; r++) {
            int row = row0 + q4 * 4 + r;
            int h = tile * 16 + l15;
            if (row < V) {
                float v = acc[tile][r] + bias[h];
                unsigned pk = __builtin_amdgcn_cvt_pk_fp8_f32(v, v, 0, false);
                hvb[(size_t)row * 128 + h] = (unsigned char)(pk & 0xff);
            }
        }
    }
}

// ---------- per-node aggregate: LDS-broadcast records + packed f32x2 FMA ----------
__global__ __launch_bounds__(256) void k_node(const uint2* __restrict__ esort,
                                              const unsigned char* __restrict__ hvb,
                                              const int* __restrict__ row_start,
                                              unsigned short* __restrict__ Xbf, int V) {
    __shared__ uint2 recbuf[4][64];
    const int w = threadIdx.x >> 6;
    const int lane = threadIdx.x & 63;
    const int v = blockIdx.x * 4 + w;
    if (v >= V) return;
    const int beg = row_start[v];
    const int ne = row_start[v + 1] - beg;
    const int l15 = lane & 15, grp = lane >> 4;

    f32x2 acc2[4];
#pragma unroll
    for (int q = 0; q < 4; q++) acc2[q] = (f32x2)(0.f);

    if (ne > 0) {
        float ssum = 0.f;
        for (int c0 = 0; c0 < ne; c0 += 64) {
            int n = min(64, ne - c0);
            uint2 r = make_uint2(0u, 0u);       // a=0 for lanes >= n
            if (lane < n) r = esort[beg + c0 + lane];
            ssum += __uint_as_float(r.x);
            recbuf[w][lane] = r;                // wave-synchronous LDS stage
            int nj = (n + 3) >> 2;
            for (int jj = 0; jj < nj; jj++) {
                uint2 p = recbuf[w][jj * 4 + grp];  // 16-lane broadcast read
                float aj = __uint_as_float(p.x);
                int sj = (int)p.y;
                uint2 p8 = *(const uint2*)&hvb[(size_t)sj * 128 + l15 * 8];
                f32x2 f0 = __builtin_amdgcn_cvt_pk_f32_fp8(p8.x, false);
                f32x2 f1 = __builtin_amdgcn_cvt_pk_f32_fp8(p8.x, true);
                f32x2 f2 = __builtin_amdgcn_cvt_pk_f32_fp8(p8.y, false);
                f32x2 f3 = __builtin_amdgcn_cvt_pk_f32_fp8(p8.y, true);
                f32x2 aj2 = {aj, aj};
                acc2[0] = f0 * aj2 + acc2[0];   // v_pk_fma_f32
                acc2[1] = f1 * aj2 + acc2[1];
                acc2[2] = f2 * aj2 + acc2[2];
                acc2[3] = f3 * aj2 + acc2[3];
            }
        }
#pragma unroll
        for (int o = 32; o; o >>= 1) ssum += __shfl_xor(ssum, o, 64);
        float inv = 1.f / ssum;
        f32x2 inv2 = {inv, inv};
#pragma unroll
        for (int q = 0; q < 4; q++) {
            f32x2 u = acc2[q];
            u[0] += __shfl_xor(u[0], 16, 64);
            u[1] += __shfl_xor(u[1], 16, 64);
            u[0] += __shfl_xor(u[0], 32, 64);
            u[1] += __shfl_xor(u[1], 32, 64);
            acc2[q] = u * inv2;
        }
    }
    if (lane < 16) {
        ushort4 o0, o1;
        o0.x = f2b(elu_fast(acc2[0][0]));
        o0.y = f2b(elu_fast(acc2[0][1]));
        o0.z = f2b(elu_fast(acc2[1][0]));
        o0.w = f2b(elu_fast(acc2[1][1]));
        o1.x = f2b(elu_fast(acc2[2][0]));
        o1.y = f2b(elu_fast(acc2[2][1]));
        o1.z = f2b(elu_fast(acc2[3][0]));
        o1.w = f2b(elu_fast(acc2[3][1]));
        *(ushort4*)&Xbf[(size_t)v * 256 + l15 * 8] = o0;
        *(ushort4*)&Xbf[(size_t)v * 256 + l15 * 8 + 4] = o1;
    }
}

// ---------- gate GEMM: LDS-staged A pipeline; two 32-row halves + B ping-pong ----------
__global__ __launch_bounds__(512, 4) void k_gates(const unsigned short* __restrict__ Xbf,
                                                  const unsigned short* __restrict__ Bt,
                                                  const float* __restrict__ b_ih,
                                                  const float* __restrict__ b_hh,
                                                  float* __restrict__ out, int V) {
    __shared__ __align__(16) unsigned short Abuf[2][64 * 256];  // 2 x 32KB
    const int t = threadIdx.x;
    const int w = t >> 6, lane = t & 63;
    const int l15 = lane & 15, q4 = lane >> 4;
    const int h = w * 16 + l15;
    const int nchunks = (V + 63) >> 6;
    const int hslot = 16 + w * 2 + (l15 >> 3);
    const int hsub = h & 7;

    const float bi0 = b_ih[h] + b_hh[h];
    const float bi1 = b_ih[h + 128] + b_hh[h + 128];
    const float bi2 = b_ih[h + 256];
    const float bi3 = b_hh[h + 256];

    const unsigned short* bbase = Bt + (((size_t)w * 24) << 9) + lane * 8;

    {
        const char* base = (const char*)Xbf + (size_t)blockIdx.x * 64 * 512;
        char* ldst = (char*)&Abuf[0][0];
#pragma unroll
        for (int it = 0; it < 4; it++) {
            int idx = it * 512 + t;
            int o = idx * 16;
            int row = idx >> 5;
            int slot = idx & 31;
            int go = (row << 9) + ((slot ^ (row & 7)) << 4);
            async_copy16(base + go, ldst + o);
        }
    }
    __syncthreads();

    int cur = 0;
    for (int chunk = blockIdx.x; chunk < nchunks; chunk += 512) {
        int nextc = chunk + 512;
        if (nextc < nchunks) {
            const char* base = (const char*)Xbf + (size_t)nextc * 64 * 512;
            char* ldst = (char*)&Abuf[cur ^ 1][0];
#pragma unroll
            for (int it = 0; it < 4; it++) {
                int idx = it * 512 + t;
                int o = idx * 16;
                int row = idx >> 5;
                int slot = idx & 31;
                int go = (row << 9) + ((slot ^ (row & 7)) << 4);
                async_copy16(base + go, ldst + o);
            }
        }

        const int rowbase = chunk * 64;
        const unsigned short* ab = &Abuf[cur][0];

#pragma unroll 1
        for (int rh = 0; rh < 2; rh++) {
            f32x4 acc[2][4];
#pragma unroll
            for (int i = 0; i < 2; i++)
#pragma unroll
                for (int j = 0; j < 4; j++) acc[i][j] = (f32x4)(0.f);

            const int rbase = rh * 32;
            short8v b0A = *(const short8v*)(bbase + ((size_t)0 << 9));
            short8v b1A = *(const short8v*)(bbase + ((size_t)8 << 9));
            short8v b2A = *(const short8v*)(bbase + ((size_t)16 << 9));
#pragma unroll 1
            for (int kc = 0; kc < 8; kc++) {
                short8v b0N, b1N, b2N;
                if (kc < 7) {
                    b0N = *(const short8v*)(bbase + ((size_t)(kc + 1) << 9));
                    b1N = *(const short8v*)(bbase + ((size_t)(8 + kc + 1) << 9));
                    b2N = *(const short8v*)(bbase + ((size_t)(16 + kc + 1) << 9));
                }
                const int s = ((kc * 4 + q4) ^ (l15 & 7)) << 3;
                short8v a0 = *(const short8v*)&ab[(rbase + l15) * 256 + s];
                short8v a1 = *(const short8v*)&ab[(rbase + 16 + l15) * 256 + s];
                acc[0][0] = __builtin_amdgcn_mfma_f32_16x16x32_bf16(a0, b0A, acc[0][0], 0, 0, 0);
                acc[1][0] = __builtin_amdgcn_mfma_f32_16x16x32_bf16(a1, b0A, acc[1][0], 0, 0, 0);
                acc[0][1] = __builtin_amdgcn_mfma_f32_16x16x32_bf16(a0, b1A, acc[0][1], 0, 0, 0);
                acc[1][1] = __builtin_amdgcn_mfma_f32_16x16x32_bf16(a1, b1A, acc[1][1], 0, 0, 0);
                if (kc < 4) {
                    acc[0][2] = __builtin_amdgcn_mfma_f32_16x16x32_bf16(a0, b2A, acc[0][2], 0, 0, 0);
                    acc[1][2] = __builtin_amdgcn_mfma_f32_16x16x32_bf16(a1, b2A, acc[1][2], 0, 0, 0);
                } else {
                    acc[0][3] = __builtin_amdgcn_mfma_f32_16x16x32_bf16(a0, b2A, acc[0][3], 0, 0, 0);
                    acc[1][3] = __builtin_amdgcn_mfma_f32_16x16x32_bf16(a1, b2A, acc[1][3], 0, 0, 0);
                }
                b0A = b0N; b1A = b1N; b2A = b2N;
            }

#pragma unroll
            for (int rt = 0; rt < 2; rt++) {
#pragma unroll
                for (int i = 0; i < 4; i++) {
                    int rowl = rbase + rt * 16 + q4 * 4 + i;
                    int row = rowbase + rowl;
                    if (row >= V) continue;
                    float ho = b2f(ab[rowl * 256 + ((hslot ^ (rowl & 7)) << 3) + hsub]);
                    float g0 = acc[rt][0][i] + bi0;
                    float g1 = acc[rt][1][i] + bi1;
                    float g2 = acc[rt][2][i] + bi2;
                    float g3 = acc[rt][3][i] + bi3;
                    float rr = 1.f / (1.f + __expf(-g0));
                    float z  = 1.f / (1.f + __expf(-g1));
                    float x2 = g2 + rr * g3;
                    float e2 = __expf(2.f * x2);
                    float nn = 1.f - 2.f / (e2 + 1.f);  // tanh(x2)
                    float hn = (1.f - z) * nn + z * ho;
                    __builtin_nontemporal_store(hn > 0.f ? hn : 0.f,
                                                &out[(size_t)row * 128 + h]);
                }
            }
        }

        __syncthreads();
        cur ^= 1;
    }
}

extern "C" void kernel_launch(void* const* d_in, const int* in_sizes, int n_in,
                              void* d_out, int out_size, void* d_ws, size_t ws_size,
                              hipStream_t stream) {
    const float* edge_logits = (const float*)d_in[0];
    const float* node_feats  = (const float*)d_in[1];
    const float* W_proj      = (const float*)d_in[2];
    const float* b_proj      = (const float*)d_in[3];
    const float* w_ih        = (const float*)d_in[4];
    const float* w_hh        = (const float*)d_in[5];
    const float* b_ih        = (const float*)d_in[6];
    const float* b_hh        = (const float*)d_in[7];
    const int*   src         = (const int*)d_in[8];
    const int*   dst         = (const int*)d_in[9];
    float* out = (float*)d_out;

    const int E = in_sizes[0];
    const int V = in_sizes[1] / FDIM;
    const int nb = (V + 255) / 256;      // <= 256
    const int nbuck = (E + 2047) >> 11;  // <= 512 (E <= 1M)

    // workspace layout (16B aligned)
    unsigned short* Xbf = (unsigned short*)d_ws;            // V*256 shorts
    unsigned char*  hvb = (unsigned char*)(Xbf + (size_t)V * 256);  // V*128 bytes (fp8)
    unsigned short* Wb  = (unsigned short*)(hvb + (size_t)V * 128); // 128*128
    unsigned short* Bt  = Wb + 128 * 128;                   // 98304 shorts (192 KB)
    uint2* esort   = (uint2*)(Bt + 98304);                  // E * 8B
    uint2* staging = esort + E;                             // E * 8B
    unsigned short* slot = (unsigned short*)(staging + E);  // E * 2B
    int*   deg       = (int*)(slot + ((E + 1) & ~1));       // V
    int*   bfill     = deg + V;                             // 512
    int*   row_start = bfill + 512;                         // V+1
    int*   bsum      = row_start + V + 1;                   // 256

    int nz = V + 512;
    k_zero<<<(nz + 255) / 256, 256, 0, stream>>>(deg, nz);

    int eb = (E + 255) / 256;
    k_deg<<<eb, 256, 0, stream>>>(dst, deg, slot, E);
    k_scan1<<<nb, 256, 0, stream>>>(deg, bsum, V);
    k_scan2<<<1, 256, 0, stream>>>(bsum, nb, row_start, V);
    k_scan3<<<nb, 256, 0, stream>>>(deg, bsum, row_start, V);

    int sb = (E + 4095) / 4096;
    k_scat1<<<sb, 512, 0, stream>>>(dst, src, edge_logits, row_start, slot, bfill, staging, E);
    k_scat2<<<nbuck, 256, 0, stream>>>(staging, esort, E);

    k_prep_W<<<64, 256, 0, stream>>>(W_proj, Wb);
    k_prep_B<<<384, 256, 0, stream>>>(w_ih, w_hh, Bt);

    int hb = (V + 63) / 64;
    k_hv<<<hb, 256, 0, stream>>>(node_feats, Wb, b_proj, Xbf, hvb, V);

    int nbk = (V + 3) / 4;
    k_node<<<nbk, 256, 0, stream>>>(esort, hvb, row_start, Xbf, V);

    k_gates<<<512, 512, 0, stream>>>(Xbf, Bt, b_ih, b_hh, out, V);
}

// Round 22
// 152.431 us; speedup vs baseline: 1.0439x; 1.0439x over previous
//
#include <hip/hip_runtime.h>
#include <hip/hip_bf16.h>
#include <math.h>

#define FDIM 128

typedef __attribute__((ext_vector_type(8))) short short8v;
typedef __attribute__((ext_vector_type(4))) float f32x4;
typedef __attribute__((ext_vector_type(2))) float f32x2;

__device__ inline unsigned short f2b(float f) {
    union { float f; unsigned u; } c{f};
    unsigned r = c.u + 0x7fff + ((c.u >> 16) & 1);  // RNE
    return (unsigned short)(r >> 16);
}
__device__ inline float b2f(unsigned short b) {
    return __uint_as_float(((unsigned)b) << 16);
}
// fast ELU negative branch: __expf-1 (cancellation error ~1e-6, invisible in bf16)
__device__ inline float elu_fast(float x) {
    return x > 0.f ? x : __expf(x) - 1.f;
}

__device__ inline void async_copy16(const void* gsrc, void* lds) {
    __builtin_amdgcn_global_load_lds(
        (const __attribute__((address_space(1))) unsigned int*)gsrc,
        (__attribute__((address_space(3))) unsigned int*)lds,
        16, 0, 0);
}

// ---------- zero scratch ----------
__global__ __launch_bounds__(256) void k_zero(int* __restrict__ p, int n) {
    int i = blockIdx.x * 256 + threadIdx.x;
    if (i < n) p[i] = 0;
}

// ---------- CSR build: histogram + per-edge slot capture (one atomic pass) ----------
__global__ __launch_bounds__(256) void k_deg(const int* __restrict__ dst,
                                             int* __restrict__ deg,
                                             unsigned short* __restrict__ slot, int E) {
    int e = blockIdx.x * 256 + threadIdx.x;
    if (e >= E) return;
    slot[e] = (unsigned short)atomicAdd(&deg[dst[e]], 1);
}

__global__ __launch_bounds__(256) void k_scan1(const int* __restrict__ deg,
                                               int* __restrict__ bsum, int V) {
    int i = blockIdx.x * 256 + threadIdx.x;
    int x = (i < V) ? deg[i] : 0;
#pragma unroll
    for (int o = 32; o; o >>= 1) x += __shfl_xor(x, o, 64);
    __shared__ int sh[4];
    int w = threadIdx.x >> 6, lane = threadIdx.x & 63;
    if (lane == 0) sh[w] = x;
    __syncthreads();
    if (threadIdx.x == 0) bsum[blockIdx.x] = sh[0] + sh[1] + sh[2] + sh[3];
}

__global__ __launch_bounds__(256) void k_scan2(int* __restrict__ bsum, int nb,
                                               int* __restrict__ row_start, int V) {
    __shared__ int sh[256];
    int t = threadIdx.x;
    int x = (t < nb) ? bsum[t] : 0;
    sh[t] = x;
    __syncthreads();
    int val = x;
    for (int o = 1; o < 256; o <<= 1) {
        int y = (t >= o) ? sh[t - o] : 0;
        __syncthreads();
        val += y;
        sh[t] = val;
        __syncthreads();
    }
    if (t < nb) bsum[t] = val - x;
    if (t == 255) row_start[V] = val;
}

// wave-level scan version (1 barrier instead of 16)
__global__ __launch_bounds__(256) void k_scan3(const int* __restrict__ deg,
                                               const int* __restrict__ bsum,
                                               int* __restrict__ row_start, int V) {
    __shared__ int wsum[4];
    const int t = threadIdx.x;
    const int w = t >> 6, lane = t & 63;
    const int i = blockIdx.x * 256 + t;
    int x = (i < V) ? deg[i] : 0;
    int val = x;
#pragma unroll
    for (int o = 1; o < 64; o <<= 1) {
        int y = __shfl_up(val, o, 64);
        if (lane >= o) val += y;
    }
    if (lane == 63) wsum[w] = val;
    __syncthreads();
    int base = 0;
#pragma unroll
    for (int ww = 0; ww < 3; ww++)
        if (ww < w) base += wsum[ww];
    if (i < V) row_start[i] = bsum[blockIdx.x] + base + val - x;
}

// ---------- scatter pass A (atomic-free): o = row_start[dst] + slot[e];
// bucket by o>>11, block-local LDS bucket sort (wave-level scan), contiguous runs.
__global__ __launch_bounds__(512) void k_scat1(const int* __restrict__ dst,
                                               const int* __restrict__ src,
                                               const float* __restrict__ logits,
                                               const int* __restrict__ row_start,
                                               const unsigned short* __restrict__ slot,
                                               int* __restrict__ bfill,
                                               uint2* __restrict__ staging, int E) {
    __shared__ int lhist[512];
    __shared__ int lscan[512];
    __shared__ int lgbase[512];
    __shared__ int wsum[8];
    __shared__ uint2 lrec[4096];
    __shared__ unsigned short lbkt[4096];
    const int t = threadIdx.x;
    const int wv = t >> 6, lane = t & 63;
    const int base = blockIdx.x * 4096;
    const int tot = min(4096, E - base);

    lhist[t] = 0;
    __syncthreads();

    uint2 rec[8];
    int bi[8], ri[8];
#pragma unroll
    for (int i = 0; i < 8; i++) {
        int e = base + i * 512 + t;
        if (e - base < tot) {
            int d = dst[e];
            int o = row_start[d] + (int)slot[e];
            rec[i].x = __float_as_uint(__expf(logits[e]));
            rec[i].y = ((unsigned)src[e] & 0xffffu) | ((unsigned)(o & 2047) << 16);
            bi[i] = o >> 11;
            ri[i] = atomicAdd(&lhist[bi[i]], 1);
        } else {
            bi[i] = -1;
        }
    }
    __syncthreads();

    // exclusive scan of lhist: wave shfl_up scan + 1 barrier for wave sums
    int hv = lhist[t];
    int val = hv;
#pragma unroll
    for (int o = 1; o < 64; o <<= 1) {
        int y = __shfl_up(val, o, 64);
        if (lane >= o) val += y;
    }
    if (lane == 63) wsum[wv] = val;
    __syncthreads();
    int wbase = 0;
#pragma unroll
    for (int ww = 0; ww < 7; ww++)
        if (ww < wv) wbase += wsum[ww];
    int excl = wbase + val - hv;
    if (hv > 0) lgbase[t] = atomicAdd(&bfill[t], hv);
    lscan[t] = excl;
    __syncthreads();

#pragma unroll
    for (int i = 0; i < 8; i++) {
        if (bi[i] >= 0) {
            int pos = lscan[bi[i]] + ri[i];
            lrec[pos] = rec[i];
            lbkt[pos] = (unsigned short)bi[i];
        }
    }
    __syncthreads();

    for (int idx = t; idx < tot; idx += 512) {
        int b = lbkt[idx];
        int gp = (b << 11) + lgbase[b] + (idx - lscan[b]);
        staging[gp] = lrec[idx];
    }
}

// ---------- scatter pass B: permute each 2048-bucket via LDS, linear write.
__global__ __launch_bounds__(256) void k_scat2(const uint2* __restrict__ staging,
                                               uint2* __restrict__ esort, int E) {
    __shared__ uint2 perm[2048];
    const int t = threadIdx.x;
    const int base = blockIdx.x << 11;
    const int n = min(2048, E - base);
    for (int i = t; i < n; i += 256) {
        uint2 r = staging[base + i];
        perm[r.y >> 16] = make_uint2(r.x, r.y & 0xffffu);
    }
    __syncthreads();
    for (int i = t; i < n; i += 256)
        esort[base + i] = perm[i];
}

// ---------- prep: fp32 -> bf16; nf goes into right half of Xbf ----------
__global__ __launch_bounds__(256) void k_cvt_nf(const float* __restrict__ nf,
                                                unsigned short* __restrict__ Xbf, int n4) {
    int i = blockIdx.x * 256 + threadIdx.x;
    if (i >= n4) return;
    float4 v = *(const float4*)&nf[(size_t)i * 4];
    ushort4 o;
    o.x = f2b(v.x); o.y = f2b(v.y); o.z = f2b(v.z); o.w = f2b(v.w);
    int row = i >> 5, col = (i & 31) * 4;
    *(ushort4*)&Xbf[(size_t)row * 256 + 128 + col] = o;
}

__global__ __launch_bounds__(256) void k_prep_W(const float* __restrict__ W,
                                                unsigned short* __restrict__ Wb) {
    int i = blockIdx.x * 256 + threadIdx.x;  // 16384
    Wb[i] = f2b(W[i]);
}

// Bt layout: bucket (cgrp, ct, kc) of 512 shorts; within = q4*128 + l15*8 + j.
__global__ __launch_bounds__(256) void k_prep_B(const float* __restrict__ w_ih,
                                                const float* __restrict__ w_hh,
                                                unsigned short* __restrict__ Bt) {
    int i = blockIdx.x * 256 + threadIdx.x;  // 98304 shorts total
    if (i >= 98304) return;
    int bucket = i >> 9;
    int within = i & 511;
    int kc = bucket & 7;
    int ct = (bucket >> 3) % 3;
    int cgrp = bucket / 24;
    int q4 = within >> 7;
    int l15 = (within >> 3) & 15;
    int j = within & 7;
    int k = kc * 32 + q4 * 8 + j;
    int h = cgrp * 16 + l15;
    float v;
    if (ct < 2) {
        int jrow = ct * 128 + h;
        v = (k < 128) ? w_ih[(size_t)jrow * 128 + k]
                      : w_hh[(size_t)jrow * 128 + (k - 128)];
    } else {
        v = (kc < 4) ? w_ih[(size_t)(256 + h) * 128 + k]
                     : w_hh[(size_t)(256 + h) * 128 + (k - 128)];
    }
    Bt[i] = f2b(v);
}

// ---------- hv(fp8 e4m3) = fp8( nf_bf @ Wb^T + b_proj ) ----------
__global__ __launch_bounds__(256) void k_hv(const unsigned short* __restrict__ Xbf,
                                            const unsigned short* __restrict__ Wb,
                                            const float* __restrict__ bias,
                                            unsigned char* __restrict__ hvb, int V) {
    __shared__ unsigned short Wl[128][136];
    const int t = threadIdx.x;
    {
        int row = t >> 1, half = (t & 1) * 64;
        const float4* s = (const float4*)&Wb[row * 128 + half];
#pragma unroll
        for (int q = 0; q < 8; q++) {
            float4 v = s[q];
            *(float4*)&Wl[row][half + q * 8] = v;
        }
    }
    __syncthreads();
    const int w = t >> 6, lane = t & 63;
    const int row0 = blockIdx.x * 64 + w * 16;
    int arow = row0 + (lane & 15);
    if (arow >= V) arow = V - 1;
    const int kl = (lane >> 4) * 8;
    f32x4 acc[8];
#pragma unroll
    for (int i = 0; i < 8; i++) acc[i] = (f32x4)(0.f);

    for (int kc = 0; kc < 4; kc++) {
        short8v a = *(const short8v*)&Xbf[(size_t)arow * 256 + 128 + kc * 32 + kl];
#pragma unroll
        for (int tile = 0; tile < 8; tile++) {
            short8v b = *(const short8v*)&Wl[tile * 16 + (lane & 15)][kc * 32 + kl];
            acc[tile] = __builtin_amdgcn_mfma_f32_16x16x32_bf16(a, b, acc[tile], 0, 0, 0);
        }
    }
#pragma unroll
    for (int tile = 0; tile < 8; tile++) {
#pragma unroll
        for (int r = 0; r < 4; r++) {
            int row = row0 + (lane >> 4) * 4 + r;
            int h = tile * 16 + (lane & 15);
            if (row < V) {
                float v = acc[tile][r] + bias[h];
                unsigned pk = __builtin_amdgcn_cvt_pk_fp8_f32(v, v, 0, false);
                hvb[(size_t)row * 128 + h] = (unsigned char)(pk & 0xff);
            }
        }
    }
}

// ---------- per-node aggregate: shuffle distribution + packed f32x2 FMA,
// fp8 hv gather, fast-ELU tail ----------
__global__ __launch_bounds__(256) void k_node(const uint2* __restrict__ esort,
                                              const unsigned char* __restrict__ hvb,
                                              const int* __restrict__ row_start,
                                              unsigned short* __restrict__ Xbf, int V) {
    const int w = threadIdx.x >> 6;
    const int lane = threadIdx.x & 63;
    const int v = blockIdx.x * 4 + w;
    if (v >= V) return;
    const int beg = row_start[v];
    const int ne = row_start[v + 1] - beg;
    const int l15 = lane & 15, grp = lane >> 4;

    f32x2 acc2[4];
#pragma unroll
    for (int q = 0; q < 4; q++) acc2[q] = (f32x2)(0.f);

    if (ne > 0) {
        float ssum = 0.f;
        for (int c0 = 0; c0 < ne; c0 += 64) {
            int n = min(64, ne - c0);
            float a = 0.f;
            int s = 0;
            if (lane < n) {
                uint2 p = esort[beg + c0 + lane];
                a = __uint_as_float(p.x);
                s = (int)p.y;
            }
            ssum += a;
            int nj = (n + 3) >> 2;
            for (int jj = 0; jj < nj; jj++) {
                int j = jj * 4 + grp;           // lanes >= n carry a=0
                float aj = __shfl(a, j, 64);
                int sj = __shfl(s, j, 64);
                uint2 p8 = *(const uint2*)&hvb[(size_t)sj * 128 + l15 * 8];
                f32x2 f0 = __builtin_amdgcn_cvt_pk_f32_fp8(p8.x, false);
                f32x2 f1 = __builtin_amdgcn_cvt_pk_f32_fp8(p8.x, true);
                f32x2 f2 = __builtin_amdgcn_cvt_pk_f32_fp8(p8.y, false);
                f32x2 f3 = __builtin_amdgcn_cvt_pk_f32_fp8(p8.y, true);
                f32x2 aj2 = {aj, aj};
                acc2[0] = f0 * aj2 + acc2[0];   // v_pk_fma_f32
                acc2[1] = f1 * aj2 + acc2[1];
                acc2[2] = f2 * aj2 + acc2[2];
                acc2[3] = f3 * aj2 + acc2[3];
            }
        }
#pragma unroll
        for (int o = 32; o; o >>= 1) ssum += __shfl_xor(ssum, o, 64);
        float inv = 1.f / ssum;
        f32x2 inv2 = {inv, inv};
#pragma unroll
        for (int q = 0; q < 4; q++) {
            f32x2 u = acc2[q];
            u[0] += __shfl_xor(u[0], 16, 64);
            u[1] += __shfl_xor(u[1], 16, 64);
            u[0] += __shfl_xor(u[0], 32, 64);
            u[1] += __shfl_xor(u[1], 32, 64);
            acc2[q] = u * inv2;
        }
    }
    if (lane < 16) {
        ushort4 o0, o1;
        o0.x = f2b(elu_fast(acc2[0][0]));
        o0.y = f2b(elu_fast(acc2[0][1]));
        o0.z = f2b(elu_fast(acc2[1][0]));
        o0.w = f2b(elu_fast(acc2[1][1]));
        o1.x = f2b(elu_fast(acc2[2][0]));
        o1.y = f2b(elu_fast(acc2[2][1]));
        o1.z = f2b(elu_fast(acc2[3][0]));
        o1.w = f2b(elu_fast(acc2[3][1]));
        *(ushort4*)&Xbf[(size_t)v * 256 + l15 * 8] = o0;
        *(ushort4*)&Xbf[(size_t)v * 256 + l15 * 8 + 4] = o1;
    }
}

// ---------- gate GEMM: LDS-staged A pipeline; two 32-row halves (acc[2][4])
// + B ping-pong -> ~95 regs, 4 waves/SIMD; NT stores for write-only out ----------
__global__ __launch_bounds__(512, 4) void k_gates(const unsigned short* __restrict__ Xbf,
                                                  const unsigned short* __restrict__ Bt,
                                                  const float* __restrict__ b_ih,
                                                  const float* __restrict__ b_hh,
                                                  float* __restrict__ out, int V) {
    __shared__ __align__(16) unsigned short Abuf[2][64 * 256];  // 2 x 32KB
    const int t = threadIdx.x;
    const int w = t >> 6, lane = t & 63;   // w = cgrp 0..7
    const int l15 = lane & 15, q4 = lane >> 4;
    const int h = w * 16 + l15;
    const int nchunks = (V + 63) >> 6;
    const int hslot = 16 + w * 2 + (l15 >> 3);
    const int hsub = h & 7;

    const float bi0 = b_ih[h] + b_hh[h];
    const float bi1 = b_ih[h + 128] + b_hh[h + 128];
    const float bi2 = b_ih[h + 256];
    const float bi3 = b_hh[h + 256];

    const unsigned short* bbase = Bt + (((size_t)w * 24) << 9) + lane * 8;

    {   // prologue: stage first chunk
        const char* base = (const char*)Xbf + (size_t)blockIdx.x * 64 * 512;
        char* ldst = (char*)&Abuf[0][0];
#pragma unroll
        for (int it = 0; it < 4; it++) {
            int idx = it * 512 + t;
            int o = idx * 16;
            int row = idx >> 5;
            int slot = idx & 31;
            int go = (row << 9) + ((slot ^ (row & 7)) << 4);
            async_copy16(base + go, ldst + o);
        }
    }
    __syncthreads();

    int cur = 0;
    for (int chunk = blockIdx.x; chunk < nchunks; chunk += 512) {
        int nextc = chunk + 512;
        if (nextc < nchunks) {
            const char* base = (const char*)Xbf + (size_t)nextc * 64 * 512;
            char* ldst = (char*)&Abuf[cur ^ 1][0];
#pragma unroll
            for (int it = 0; it < 4; it++) {
                int idx = it * 512 + t;
                int o = idx * 16;
                int row = idx >> 5;
                int slot = idx & 31;
                int go = (row << 9) + ((slot ^ (row & 7)) << 4);
                async_copy16(base + go, ldst + o);
            }
        }

        const int rowbase = chunk * 64;
        const unsigned short* ab = &Abuf[cur][0];

#pragma unroll 1
        for (int rh = 0; rh < 2; rh++) {
            f32x4 acc[2][4];
#pragma unroll
            for (int i = 0; i < 2; i++)
#pragma unroll
                for (int j = 0; j < 4; j++) acc[i][j] = (f32x4)(0.f);

            const int rbase = rh * 32;
            short8v b0A = *(const short8v*)(bbase + ((size_t)0 << 9));
            short8v b1A = *(const short8v*)(bbase + ((size_t)8 << 9));
            short8v b2A = *(const short8v*)(bbase + ((size_t)16 << 9));
#pragma unroll 1
            for (int kc = 0; kc < 8; kc++) {
                short8v b0N, b1N, b2N;
                if (kc < 7) {
                    b0N = *(const short8v*)(bbase + ((size_t)(kc + 1) << 9));
                    b1N = *(const short8v*)(bbase + ((size_t)(8 + kc + 1) << 9));
                    b2N = *(const short8v*)(bbase + ((size_t)(16 + kc + 1) << 9));
                }
                const int s = ((kc * 4 + q4) ^ (l15 & 7)) << 3;
                short8v a0 = *(const short8v*)&ab[(rbase + l15) * 256 + s];
                short8v a1 = *(const short8v*)&ab[(rbase + 16 + l15) * 256 + s];
                acc[0][0] = __builtin_amdgcn_mfma_f32_16x16x32_bf16(a0, b0A, acc[0][0], 0, 0, 0);
                acc[1][0] = __builtin_amdgcn_mfma_f32_16x16x32_bf16(a1, b0A, acc[1][0], 0, 0, 0);
                acc[0][1] = __builtin_amdgcn_mfma_f32_16x16x32_bf16(a0, b1A, acc[0][1], 0, 0, 0);
                acc[1][1] = __builtin_amdgcn_mfma_f32_16x16x32_bf16(a1, b1A, acc[1][1], 0, 0, 0);
                if (kc < 4) {
                    acc[0][2] = __builtin_amdgcn_mfma_f32_16x16x32_bf16(a0, b2A, acc[0][2], 0, 0, 0);
                    acc[1][2] = __builtin_amdgcn_mfma_f32_16x16x32_bf16(a1, b2A, acc[1][2], 0, 0, 0);
                } else {
                    acc[0][3] = __builtin_amdgcn_mfma_f32_16x16x32_bf16(a0, b2A, acc[0][3], 0, 0, 0);
                    acc[1][3] = __builtin_amdgcn_mfma_f32_16x16x32_bf16(a1, b2A, acc[1][3], 0, 0, 0);
                }
                b0A = b0N; b1A = b1N; b2A = b2N;
            }

#pragma unroll
            for (int rt = 0; rt < 2; rt++) {
#pragma unroll
                for (int i = 0; i < 4; i++) {
                    int rowl = rbase + rt * 16 + q4 * 4 + i;
                    int row = rowbase + rowl;
                    if (row >= V) continue;
                    float ho = b2f(ab[rowl * 256 + ((hslot ^ (rowl & 7)) << 3) + hsub]);
                    float g0 = acc[rt][0][i] + bi0;
                    float g1 = acc[rt][1][i] + bi1;
                    float g2 = acc[rt][2][i] + bi2;
                    float g3 = acc[rt][3][i] + bi3;
                    float rr = 1.f / (1.f + __expf(-g0));
                    float z  = 1.f / (1.f + __expf(-g1));
                    float x2 = g2 + rr * g3;
                    float e2 = __expf(2.f * x2);
                    float nn = 1.f - 2.f / (e2 + 1.f);  // tanh(x2)
                    float hn = (1.f - z) * nn + z * ho;
                    __builtin_nontemporal_store(hn > 0.f ? hn : 0.f,
                                                &out[(size_t)row * 128 + h]);
                }
            }
        }

        __syncthreads();
        cur ^= 1;
    }
}

extern "C" void kernel_launch(void* const* d_in, const int* in_sizes, int n_in,
                              void* d_out, int out_size, void* d_ws, size_t ws_size,
                              hipStream_t stream) {
    const float* edge_logits = (const float*)d_in[0];
    const float* node_feats  = (const float*)d_in[1];
    const float* W_proj      = (const float*)d_in[2];
    const float* b_proj      = (const float*)d_in[3];
    const float* w_ih        = (const float*)d_in[4];
    const float* w_hh        = (const float*)d_in[5];
    const float* b_ih        = (const float*)d_in[6];
    const float* b_hh        = (const float*)d_in[7];
    const int*   src         = (const int*)d_in[8];
    const int*   dst         = (const int*)d_in[9];
    float* out = (float*)d_out;

    const int E = in_sizes[0];
    const int V = in_sizes[1] / FDIM;
    const int nb = (V + 255) / 256;      // <= 256
    const int nbuck = (E + 2047) >> 11;  // <= 512 (E <= 1M)

    // workspace layout (16B aligned)
    unsigned short* Xbf = (unsigned short*)d_ws;            // V*256 shorts
    unsigned char*  hvb = (unsigned char*)(Xbf + (size_t)V * 256);  // V*128 bytes (fp8)
    unsigned short* Wb  = (unsigned short*)(hvb + (size_t)V * 128); // 128*128
    unsigned short* Bt  = Wb + 128 * 128;                   // 98304 shorts (192 KB)
    uint2* esort   = (uint2*)(Bt + 98304);                  // E * 8B
    uint2* staging = esort + E;                             // E * 8B
    unsigned short* slot = (unsigned short*)(staging + E);  // E * 2B
    int*   deg       = (int*)(slot + ((E + 1) & ~1));       // V
    int*   bfill     = deg + V;                             // 512
    int*   row_start = bfill + 512;                         // V+1
    int*   bsum      = row_start + V + 1;                   // 256

    int nz = V + 512;
    k_zero<<<(nz + 255) / 256, 256, 0, stream>>>(deg, nz);

    int eb = (E + 255) / 256;
    k_deg<<<eb, 256, 0, stream>>>(dst, deg, slot, E);
    k_scan1<<<nb, 256, 0, stream>>>(deg, bsum, V);
    k_scan2<<<1, 256, 0, stream>>>(bsum, nb, row_start, V);
    k_scan3<<<nb, 256, 0, stream>>>(deg, bsum, row_start, V);

    int sb = (E + 4095) / 4096;
    k_scat1<<<sb, 512, 0, stream>>>(dst, src, edge_logits, row_start, slot, bfill, staging, E);
    k_scat2<<<nbuck, 256, 0, stream>>>(staging, esort, E);

    int n4 = (V * FDIM) / 4;
    k_cvt_nf<<<(n4 + 255) / 256, 256, 0, stream>>>(node_feats, Xbf, n4);
    k_prep_W<<<64, 256, 0, stream>>>(W_proj, Wb);
    k_prep_B<<<384, 256, 0, stream>>>(w_ih, w_hh, Bt);

    int hb = (V + 63) / 64;
    k_hv<<<hb, 256, 0, stream>>>(Xbf, Wb, b_proj, hvb, V);

    int nbk = (V + 3) / 4;
    k_node<<<nbk, 256, 0, stream>>>(esort, hvb, row_start, Xbf, V);

    k_gates<<<512, 512, 0, stream>>>(Xbf, Bt, b_ih, b_hh, out, V);
}